// Round 5
// baseline (359.799 us; speedup 1.0000x reference)
//
#include <hip/hip_runtime.h>
#include <math.h>

// Problem constants
#define D_FEAT   128
#define O_SIZE   256
#define N_NEUR   1024
#define STEPS_PER_WG 4
#define N_CHAIN_WG   (O_SIZE / STEPS_PER_WG)     // 64 chain blocks
#define N_WRITER_WG  192                          // out-writer blocks
#define N_BLOCKS     (N_CHAIN_WG + N_WRITER_WG)  // 256 = 1 block/CU, all resident
#define N_ITEMS      (O_SIZE * 8)                 // out work items: (t, 128-row chunk)

typedef unsigned long long ull;
typedef float floatx4 __attribute__((ext_vector_type(4)));

// Module-owned channels (persist across graph replays; generation-tagged so no
// init/invalidate pass is needed).
__device__ ull      g_chan[N_CHAIN_WG][D_FEAT];  // baton: (tag<<32)|bits(v_j), tag=(gen<<8)|g
__device__ ull      g_uchan[O_SIZE][D_FEAT];     // u:     (tag<<32)|bits(u_j), tag=(gen<<8)|t
__device__ unsigned g_uflag[O_SIZE];             // per-step ready flag = (gen<<8)|t
__device__ unsigned g_prog = 0;                  // chain progress: (gen<<8)|g of last STARTED WG
__device__ unsigned g_gen  = 1u;                 // generation; bumped by last block each launch
__device__ int      g_done = 0;                  // completion counter (reset each launch)

// Fast, safe tanh: |err| ~1e-7, no inf/nan for any input.
__device__ __forceinline__ float tanh_fast(float x) {
    x = fminf(fmaxf(x, -20.f), 20.f);
    float e = __expf(2.f * x);
    return (e - 1.f) * __builtin_amdgcn_rcpf(e + 1.f);
}

// ---------------------------------------------------------------------------
// Single fused persistent kernel.
//   bid <  64 : chain role, round-3 dataflow (coalesced W, psum 2-barrier —
//               round-4's shfl/1-barrier variant measured SLOWER; shfl chains
//               on the LDS pipe cost more than barriers among resident waves).
//               Round-5 trims: floatx4 v-broadcast reads, 4-acc FMA tree,
//               pairwise psum reduce, progress-gated polling (63 waiting WGs
//               previously generated ~340 GB/s of LLC poll traffic contending
//               with the baton stores they awaited).
//   bid >= 64 : writer role. Polls per-step flags, streams out[t] = tanh(a⊗u)
//               while the chain runs on other CUs.
// u crosses XCDs via agent-scope atomics (LLC) — plain loads would hit the
// consumer XCD's stale L2.
// ---------------------------------------------------------------------------
__global__ __launch_bounds__(1024) void fused_kernel(
    const float* __restrict__ x,
    const float* __restrict__ pos_head,
    const float* __restrict__ pos_tail,
    const float* __restrict__ W,
    const float* __restrict__ a,
    float* __restrict__ out)
{
    const int bid = blockIdx.x;
    const int tid = threadIdx.x;
    const unsigned gen = g_gen;   // stable for this launch: bumped only after all
                                  // 256 blocks have passed the end-of-kernel counter

    if (bid < N_CHAIN_WG) {
        // ------------------------- chain role ------------------------------
        __shared__ __align__(16) float v_lds[D_FEAT];
        __shared__ float psum[8][D_FEAT];
        __shared__ float ptps[8][64];
        __shared__ float red[64];

        const int g  = ((bid & 7) << 3) | (bid >> 3);   // XCD-local chain order
        const int s  = tid >> 7;      // m-block (16 rows)
        const int j  = tid & 127;     // column
        const int t0 = g * STEPS_PER_WG;

        // W[t0+k][s*16+m][j] -> w[k][m]  (64 VGPRs/thread, 256 KB/WG)
        // Coalesced: consecutive tid = consecutive j (round-4's scattered
        // variant regressed).
        float w[STEPS_PER_WG][16];
        #pragma unroll
        for (int k = 0; k < STEPS_PER_WG; ++k) {
            #pragma unroll
            for (int m = 0; m < 16; ++m)
                w[k][m] = W[((size_t)(t0 + k) * D_FEAT + (s * 16 + m)) * D_FEAT + j];
        }
        float ascal[STEPS_PER_WG];
        #pragma unroll
        for (int k = 0; k < STEPS_PER_WG; ++k)
            ascal[k] = a[(t0 + k) * N_NEUR + (t0 + k) + 1];

        if (g == 0) {
            // v0 = (sum_k scores[k,0]) * colsum(x) — runs while W loads fly.
            {
                float acc = 0.f;
                #pragma unroll 8
                for (int ii = 0; ii < 32; ++ii)
                    acc += x[(s * 32 + ii) * D_FEAT + j];
                psum[s][j] = acc;
            }
            if (tid < 512) {
                const int kb = tid >> 6, d = tid & 63;
                float acc = 0.f;
                #pragma unroll 8
                for (int kk = 0; kk < 32; ++kk)
                    acc += pos_tail[(kb * 32 + kk) * 64 + d];
                ptps[kb][d] = acc;
            }
            __syncthreads();
            if (tid < 64) {
                float ptd = 0.f;
                #pragma unroll
                for (int kb = 0; kb < 8; ++kb) ptd += ptps[kb][tid];
                red[tid] = ptd * pos_head[tid];   // pos_head row 0
            }
            __syncthreads();
            if (tid < 128) {
                float sx = 0.f;
                #pragma unroll
                for (int s8 = 0; s8 < 8; ++s8) sx += psum[s8][tid];
                float ss0 = 0.f;
                #pragma unroll
                for (int d = 0; d < 64; ++d) ss0 += red[d];
                v_lds[tid] = ss0 * sx;            // v0
            }
        } else {
            // Force ALL W/a loads complete into live VGPRs BEFORE the poll
            // loop, so the 256 KB/WG prefetch happens in parallel across all
            // WGs at kernel start instead of serially post-baton.
            float dummy = 0.f;
            #pragma unroll
            for (int k = 0; k < STEPS_PER_WG; ++k) {
                #pragma unroll
                for (int m = 0; m < 16; ++m) {
                    asm volatile("" : "+v"(w[k][m]));
                    dummy += w[k][m];
                }
                asm volatile("" : "+v"(ascal[k]));
            }
            asm volatile("" :: "v"(dummy));   // loads done HERE

            // Progress gate: far WGs (g>2) park on a single-word poll (one
            // lane, sleep(16) ~0.43us period) until WG g-2 has STARTED its
            // steps; only then do 128 lanes tight-poll the baton slots.
            // Cuts LLC poll traffic ~340 GB/s -> ~12 GB/s. The gate opens
            // ~2 hops (~4-5us) before our baton arrives, so the extra
            // barrier below is never on the hop critical path.
            if (g > 2 && tid == 0) {
                const unsigned wantp = (unsigned)(g - 2);
                for (;;) {
                    const unsigned pv = __hip_atomic_load(&g_prog, __ATOMIC_RELAXED,
                                                          __HIP_MEMORY_SCOPE_AGENT);
                    if ((pv >> 8) == gen && (pv & 0xFFu) >= wantp) break;
                    __builtin_amdgcn_s_sleep(16);
                }
            }
            __syncthreads();   // release all 128 pollers together

            // Tight poll for the baton (v vector for step t0).
            if (tid < 128) {
                const unsigned want = (gen << 8) | (unsigned)g;
                ull pk;
                for (;;) {
                    pk = __hip_atomic_load(&g_chan[g][tid], __ATOMIC_RELAXED,
                                           __HIP_MEMORY_SCOPE_AGENT);
                    if ((unsigned)(pk >> 32) == want) break;
                    __builtin_amdgcn_s_sleep(1);
                }
                v_lds[tid] = __uint_as_float((unsigned)pk);
            }
        }
        __syncthreads();   // v_lds ready; also separates g0's psum reuse

        // Announce "WG g started" (fire-and-forget hint for the progress gate;
        // correctness never depends on it — baton tags are authoritative).
        if (tid == 0)
            __hip_atomic_store(&g_prog, (gen << 8) | (unsigned)g,
                               __ATOMIC_RELAXED, __HIP_MEMORY_SCOPE_AGENT);

        // ---- steps loop: LDS-only body, NO global stores (critical path) ----
        float ureg[STEPS_PER_WG];   // u[t0+k][j], live in tid<128 only
        #pragma unroll
        for (int k = 0; k < STEPS_PER_WG; ++k) {
            // v broadcast: 4x uniform-address float4 reads (vs 16 scalar).
            const floatx4* v4 = (const floatx4*)&v_lds[s * 16];
            const floatx4 b0 = v4[0];
            const floatx4 b1 = v4[1];
            const floatx4 b2 = v4[2];
            const floatx4 b3 = v4[3];
            // 4 independent accumulators -> 2-level tree (dep chain ~32cy vs 64).
            float a0 = b0.x * w[k][ 0] + b0.y * w[k][ 1] + b0.z * w[k][ 2] + b0.w * w[k][ 3];
            float a1 = b1.x * w[k][ 4] + b1.y * w[k][ 5] + b1.z * w[k][ 6] + b1.w * w[k][ 7];
            float a2 = b2.x * w[k][ 8] + b2.y * w[k][ 9] + b2.z * w[k][10] + b2.w * w[k][11];
            float a3 = b3.x * w[k][12] + b3.y * w[k][13] + b3.z * w[k][14] + b3.w * w[k][15];
            psum[s][j] = (a0 + a1) + (a2 + a3);
            __syncthreads();

            if (tid < 128) {
                // pairwise tree over the 8 partials (dep chain ~12cy vs 32).
                const float p0 = psum[0][j] + psum[1][j];
                const float p1 = psum[2][j] + psum[3][j];
                const float p2 = psum[4][j] + psum[5][j];
                const float p3 = psum[6][j] + psum[7][j];
                const float u  = (p0 + p1) + (p2 + p3);
                ureg[k] = u;
                const float vn = tanh_fast(ascal[k] * u);
                if (k < STEPS_PER_WG - 1) {
                    v_lds[j] = vn;
                } else if (g + 1 < N_CHAIN_WG) {
                    // Baton leaves HERE — everything after is shadow time.
                    const ull pk = (((ull)((gen << 8) | (unsigned)(g + 1))) << 32) |
                                   (ull)__float_as_uint(vn);
                    __hip_atomic_store(&g_chan[g + 1][j], pk, __ATOMIC_RELAXED,
                                       __HIP_MEMORY_SCOPE_AGENT);
                }
            }
            __syncthreads();   // protects psum reuse + v_lds update
        }

        // ---- post-baton publication (overlapped with next chain WG) ----
        if (tid < 128) {
            #pragma unroll
            for (int k = 0; k < STEPS_PER_WG; ++k) {
                const int t = t0 + k;
                const ull upk = (((ull)((gen << 8) | (unsigned)t)) << 32) |
                                (ull)__float_as_uint(ureg[k]);
                __hip_atomic_store(&g_uchan[t][j], upk, __ATOMIC_RELAXED,
                                   __HIP_MEMORY_SCOPE_AGENT);
            }
        }
        __syncthreads();   // every wave's uchan stores ACKed at LLC past here
        if (tid < STEPS_PER_WG) {
            const int t = t0 + tid;
            __hip_atomic_store(&g_uflag[t], (gen << 8) | (unsigned)t,
                               __ATOMIC_RELAXED, __HIP_MEMORY_SCOPE_AGENT);
        }
    } else {
        // ------------------------- writer role -----------------------------
        // Item i -> (t = i>>3, c = i&7): 128 output rows (l = c*128..c*128+127),
        // 64 KB each. t ascends with i, so demand tracks chain production.
        const int wid = bid - N_CHAIN_WG;
        const int j4  = tid & 31;                 // float4 column
        for (int i = wid; i < N_ITEMS; i += N_WRITER_WG) {
            const int t = i >> 3;
            const int c = i & 7;
            const unsigned want = (gen << 8) | (unsigned)t;
            if (tid == 0) {   // single poller per WG: LLC poll traffic ~KB/µs
                while (__hip_atomic_load(&g_uflag[t], __ATOMIC_RELAXED,
                                         __HIP_MEMORY_SCOPE_AGENT) != want)
                    __builtin_amdgcn_s_sleep(8);
            }
            __syncthreads();

            // One-shot u read from LLC (agent atomics — never the local L2).
            const ull e0 = __hip_atomic_load(&g_uchan[t][4 * j4 + 0], __ATOMIC_RELAXED, __HIP_MEMORY_SCOPE_AGENT);
            const ull e1 = __hip_atomic_load(&g_uchan[t][4 * j4 + 1], __ATOMIC_RELAXED, __HIP_MEMORY_SCOPE_AGENT);
            const ull e2 = __hip_atomic_load(&g_uchan[t][4 * j4 + 2], __ATOMIC_RELAXED, __HIP_MEMORY_SCOPE_AGENT);
            const ull e3 = __hip_atomic_load(&g_uchan[t][4 * j4 + 3], __ATOMIC_RELAXED, __HIP_MEMORY_SCOPE_AGENT);
            const float u0 = __uint_as_float((unsigned)e0);
            const float u1 = __uint_as_float((unsigned)e1);
            const float u2 = __uint_as_float((unsigned)e2);
            const float u3 = __uint_as_float((unsigned)e3);

            const int lbase = (c << 7) + (tid >> 5);
            #pragma unroll
            for (int p = 0; p < 4; ++p) {
                const int row = (t << 10) + lbase + (p << 5);   // t*1024 + l
                const float sc = a[row];
                floatx4 r;
                r.x = tanh_fast(sc * u0);
                r.y = tanh_fast(sc * u1);
                r.z = tanh_fast(sc * u2);
                r.w = tanh_fast(sc * u3);
                __builtin_nontemporal_store(r, (floatx4*)out + (((size_t)row) << 5) + j4);
            }
        }
    }

    // Generation bump: the 256th block to finish resets g_done and advances
    // g_gen. Every block read g_gen at entry (all resident from t=0), so no
    // block can observe the bump within this launch; the next launch (stream-
    // ordered) sees it via the kernel-boundary flush.
    __syncthreads();
    if (tid == 0) {
        const int old = atomicAdd(&g_done, 1);
        if (old == N_BLOCKS - 1) {
            __hip_atomic_store(&g_done, 0, __ATOMIC_RELAXED, __HIP_MEMORY_SCOPE_AGENT);
            __hip_atomic_store(&g_gen, gen + 1u, __ATOMIC_RELAXED, __HIP_MEMORY_SCOPE_AGENT);
        }
    }
}

// ---------------------------------------------------------------------------
extern "C" void kernel_launch(void* const* d_in, const int* in_sizes, int n_in,
                              void* d_out, int out_size, void* d_ws, size_t ws_size,
                              hipStream_t stream)
{
    const float* x        = (const float*)d_in[0];
    const float* pos_head = (const float*)d_in[1];
    const float* pos_tail = (const float*)d_in[2];
    const float* W        = (const float*)d_in[3];
    const float* a        = (const float*)d_in[4];
    float*       out      = (float*)d_out;

    hipLaunchKernelGGL(fused_kernel, dim3(N_BLOCKS), dim3(1024), 0, stream,
                       x, pos_head, pos_tail, W, a, out);
}

// Round 6
// 290.641 us; speedup vs baseline: 1.2379x; 1.2379x over previous
//
#include <hip/hip_runtime.h>
#include <math.h>

// Problem constants
#define D_FEAT   128
#define O_SIZE   256
#define N_NEUR   1024
#define STEPS_PER_WG 4
#define N_CHAIN_WG   (O_SIZE / STEPS_PER_WG)     // 64 chain blocks
#define N_WRITER_WG  192                          // out-writer blocks
#define N_BLOCKS     (N_CHAIN_WG + N_WRITER_WG)  // 256 = 1 block/CU, all resident
#define N_ITEMS      (O_SIZE * 8)                 // out work items: (t, 128-row chunk)

typedef unsigned long long ull;
typedef float floatx4 __attribute__((ext_vector_type(4)));

// Module-owned channels (persist across graph replays; generation-tagged so no
// init/invalidate pass is needed).
__device__ ull      g_chan[N_CHAIN_WG][D_FEAT];  // baton: (tag<<32)|bits(v_j), tag=(gen<<8)|g
__device__ ull      g_uchan[O_SIZE][D_FEAT];     // u:     (tag<<32)|bits(u_j), tag=(gen<<8)|t
__device__ unsigned g_uflag[O_SIZE];             // per-step ready flag = (gen<<8)|t
__device__ unsigned g_gen  = 1u;                 // generation; bumped by last block each launch
__device__ int      g_done = 0;                  // completion counter (reset each launch)

// Fast, safe tanh: |err| ~1e-7, no inf/nan for any input.
__device__ __forceinline__ float tanh_fast(float x) {
    x = fminf(fmaxf(x, -20.f), 20.f);
    float e = __expf(2.f * x);
    return (e - 1.f) * __builtin_amdgcn_rcpf(e + 1.f);
}

// ---------------------------------------------------------------------------
// Single fused persistent kernel. UNBUNDLING ROUND: exact round-3 structure
// (no progress gate, no announce store — round-5's bundle regressed 150->225)
// with ONLY the step-body trims applied:
//   - 4x uniform-address floatx4 v-broadcast reads (vs 16 scalar)
//   - 4 independent FMA accumulators + 2-level tree
//   - pairwise tree over the 8 psum partials
//   bid <  64 : chain role; bid >= 64 : writer role (streams out[t] while the
//   chain runs). u crosses XCDs via agent-scope atomics (LLC).
// ---------------------------------------------------------------------------
__global__ __launch_bounds__(1024) void fused_kernel(
    const float* __restrict__ x,
    const float* __restrict__ pos_head,
    const float* __restrict__ pos_tail,
    const float* __restrict__ W,
    const float* __restrict__ a,
    float* __restrict__ out)
{
    const int bid = blockIdx.x;
    const int tid = threadIdx.x;
    const unsigned gen = g_gen;   // stable for this launch: bumped only after all
                                  // 256 blocks have passed the end-of-kernel counter

    if (bid < N_CHAIN_WG) {
        // ------------------------- chain role ------------------------------
        __shared__ __align__(16) float v_lds[D_FEAT];
        __shared__ float psum[8][D_FEAT];
        __shared__ float ptps[8][64];
        __shared__ float red[64];

        const int g  = ((bid & 7) << 3) | (bid >> 3);   // XCD-local chain order
        const int s  = tid >> 7;      // m-block (16 rows)
        const int j  = tid & 127;     // column
        const int t0 = g * STEPS_PER_WG;

        // W[t0+k][s*16+m][j] -> w[k][m]  (64 values/thread, 256 KB/WG),
        // coalesced: consecutive tid = consecutive j.
        float w[STEPS_PER_WG][16];
        #pragma unroll
        for (int k = 0; k < STEPS_PER_WG; ++k) {
            #pragma unroll
            for (int m = 0; m < 16; ++m)
                w[k][m] = W[((size_t)(t0 + k) * D_FEAT + (s * 16 + m)) * D_FEAT + j];
        }
        float ascal[STEPS_PER_WG];
        #pragma unroll
        for (int k = 0; k < STEPS_PER_WG; ++k)
            ascal[k] = a[(t0 + k) * N_NEUR + (t0 + k) + 1];

        if (g == 0) {
            // v0 = (sum_k scores[k,0]) * colsum(x) — runs while W loads fly.
            {
                float acc = 0.f;
                #pragma unroll 8
                for (int ii = 0; ii < 32; ++ii)
                    acc += x[(s * 32 + ii) * D_FEAT + j];
                psum[s][j] = acc;
            }
            if (tid < 512) {
                const int kb = tid >> 6, d = tid & 63;
                float acc = 0.f;
                #pragma unroll 8
                for (int kk = 0; kk < 32; ++kk)
                    acc += pos_tail[(kb * 32 + kk) * 64 + d];
                ptps[kb][d] = acc;
            }
            __syncthreads();
            if (tid < 64) {
                float ptd = 0.f;
                #pragma unroll
                for (int kb = 0; kb < 8; ++kb) ptd += ptps[kb][tid];
                red[tid] = ptd * pos_head[tid];   // pos_head row 0
            }
            __syncthreads();
            if (tid < 128) {
                float sx = 0.f;
                #pragma unroll
                for (int s8 = 0; s8 < 8; ++s8) sx += psum[s8][tid];
                float ss0 = 0.f;
                #pragma unroll
                for (int d = 0; d < 64; ++d) ss0 += red[d];
                v_lds[tid] = ss0 * sx;            // v0
            }
        }

        // Force ALL W/a loads complete into live VGPRs BEFORE the poll loop
        // (unconditional, exactly as round 3), so the 256 KB/WG prefetch
        // happens in parallel across all WGs at kernel start.
        float dummy = 0.f;
        #pragma unroll
        for (int k = 0; k < STEPS_PER_WG; ++k) {
            #pragma unroll
            for (int m = 0; m < 16; ++m) {
                asm volatile("" : "+v"(w[k][m]));
                dummy += w[k][m];
            }
            asm volatile("" : "+v"(ascal[k]));
        }
        asm volatile("" :: "v"(dummy));   // loads done HERE

        // Wait for the baton (v vector for step t0). g==0 already has v0.
        if (g > 0 && tid < 128) {
            const unsigned want = (gen << 8) | (unsigned)g;
            ull pk;
            for (;;) {
                pk = __hip_atomic_load(&g_chan[g][tid], __ATOMIC_RELAXED,
                                       __HIP_MEMORY_SCOPE_AGENT);
                if ((unsigned)(pk >> 32) == want) break;
                __builtin_amdgcn_s_sleep(1);
            }
            v_lds[tid] = __uint_as_float((unsigned)pk);
        }
        __syncthreads();   // v_lds ready; also separates g0's psum reuse

        // ---- steps loop: LDS-only body, NO global stores (critical path) ----
        float ureg[STEPS_PER_WG];   // u[t0+k][j], live in tid<128 only
        #pragma unroll
        for (int k = 0; k < STEPS_PER_WG; ++k) {
            // v broadcast: 4x uniform-address float4 reads (vs 16 scalar).
            const floatx4* v4 = (const floatx4*)&v_lds[s * 16];
            const floatx4 b0 = v4[0];
            const floatx4 b1 = v4[1];
            const floatx4 b2 = v4[2];
            const floatx4 b3 = v4[3];
            // 4 independent accumulators -> 2-level tree (dep chain ~32cy vs 64).
            float a0 = b0.x * w[k][ 0] + b0.y * w[k][ 1] + b0.z * w[k][ 2] + b0.w * w[k][ 3];
            float a1 = b1.x * w[k][ 4] + b1.y * w[k][ 5] + b1.z * w[k][ 6] + b1.w * w[k][ 7];
            float a2 = b2.x * w[k][ 8] + b2.y * w[k][ 9] + b2.z * w[k][10] + b2.w * w[k][11];
            float a3 = b3.x * w[k][12] + b3.y * w[k][13] + b3.z * w[k][14] + b3.w * w[k][15];
            psum[s][j] = (a0 + a1) + (a2 + a3);
            __syncthreads();

            if (tid < 128) {
                // pairwise tree over the 8 partials (dep chain ~12cy vs 32).
                const float p0 = psum[0][j] + psum[1][j];
                const float p1 = psum[2][j] + psum[3][j];
                const float p2 = psum[4][j] + psum[5][j];
                const float p3 = psum[6][j] + psum[7][j];
                const float u  = (p0 + p1) + (p2 + p3);
                ureg[k] = u;
                const float vn = tanh_fast(ascal[k] * u);
                if (k < STEPS_PER_WG - 1) {
                    v_lds[j] = vn;
                } else if (g + 1 < N_CHAIN_WG) {
                    // Baton leaves HERE — everything after is shadow time.
                    const ull pk = (((ull)((gen << 8) | (unsigned)(g + 1))) << 32) |
                                   (ull)__float_as_uint(vn);
                    __hip_atomic_store(&g_chan[g + 1][tid], pk, __ATOMIC_RELAXED,
                                       __HIP_MEMORY_SCOPE_AGENT);
                }
            }
            __syncthreads();   // protects psum reuse + v_lds update
        }

        // ---- post-baton publication (overlapped with next chain WG) ----
        if (tid < 128) {
            #pragma unroll
            for (int k = 0; k < STEPS_PER_WG; ++k) {
                const int t = t0 + k;
                const ull upk = (((ull)((gen << 8) | (unsigned)t)) << 32) |
                                (ull)__float_as_uint(ureg[k]);
                __hip_atomic_store(&g_uchan[t][tid], upk, __ATOMIC_RELAXED,
                                   __HIP_MEMORY_SCOPE_AGENT);
            }
        }
        __syncthreads();   // every wave's uchan stores ACKed at LLC past here
        if (tid < STEPS_PER_WG) {
            const int t = t0 + tid;
            __hip_atomic_store(&g_uflag[t], (gen << 8) | (unsigned)t,
                               __ATOMIC_RELAXED, __HIP_MEMORY_SCOPE_AGENT);
        }
    } else {
        // ------------------------- writer role -----------------------------
        // Item i -> (t = i>>3, c = i&7): 128 output rows, 64 KB each.
        const int wid = bid - N_CHAIN_WG;
        const int j4  = tid & 31;                 // float4 column
        for (int i = wid; i < N_ITEMS; i += N_WRITER_WG) {
            const int t = i >> 3;
            const int c = i & 7;
            const unsigned want = (gen << 8) | (unsigned)t;
            if (tid == 0) {   // single poller per WG: LLC poll traffic ~KB/µs
                while (__hip_atomic_load(&g_uflag[t], __ATOMIC_RELAXED,
                                         __HIP_MEMORY_SCOPE_AGENT) != want)
                    __builtin_amdgcn_s_sleep(8);
            }
            __syncthreads();

            // One-shot u read from LLC (agent atomics — never the local L2).
            const ull e0 = __hip_atomic_load(&g_uchan[t][4 * j4 + 0], __ATOMIC_RELAXED, __HIP_MEMORY_SCOPE_AGENT);
            const ull e1 = __hip_atomic_load(&g_uchan[t][4 * j4 + 1], __ATOMIC_RELAXED, __HIP_MEMORY_SCOPE_AGENT);
            const ull e2 = __hip_atomic_load(&g_uchan[t][4 * j4 + 2], __ATOMIC_RELAXED, __HIP_MEMORY_SCOPE_AGENT);
            const ull e3 = __hip_atomic_load(&g_uchan[t][4 * j4 + 3], __ATOMIC_RELAXED, __HIP_MEMORY_SCOPE_AGENT);
            const float u0 = __uint_as_float((unsigned)e0);
            const float u1 = __uint_as_float((unsigned)e1);
            const float u2 = __uint_as_float((unsigned)e2);
            const float u3 = __uint_as_float((unsigned)e3);

            const int lbase = (c << 7) + (tid >> 5);
            #pragma unroll
            for (int p = 0; p < 4; ++p) {
                const int row = (t << 10) + lbase + (p << 5);   // t*1024 + l
                const float sc = a[row];
                floatx4 r;
                r.x = tanh_fast(sc * u0);
                r.y = tanh_fast(sc * u1);
                r.z = tanh_fast(sc * u2);
                r.w = tanh_fast(sc * u3);
                __builtin_nontemporal_store(r, (floatx4*)out + (((size_t)row) << 5) + j4);
            }
        }
    }

    // Generation bump: the 256th block to finish resets g_done and advances
    // g_gen. Every block read g_gen at entry (all resident from t=0), so no
    // block can observe the bump within this launch; the next launch (stream-
    // ordered) sees it via the kernel-boundary flush.
    __syncthreads();
    if (tid == 0) {
        const int old = atomicAdd(&g_done, 1);
        if (old == N_BLOCKS - 1) {
            __hip_atomic_store(&g_done, 0, __ATOMIC_RELAXED, __HIP_MEMORY_SCOPE_AGENT);
            __hip_atomic_store(&g_gen, gen + 1u, __ATOMIC_RELAXED, __HIP_MEMORY_SCOPE_AGENT);
        }
    }
}

// ---------------------------------------------------------------------------
extern "C" void kernel_launch(void* const* d_in, const int* in_sizes, int n_in,
                              void* d_out, int out_size, void* d_ws, size_t ws_size,
                              hipStream_t stream)
{
    const float* x        = (const float*)d_in[0];
    const float* pos_head = (const float*)d_in[1];
    const float* pos_tail = (const float*)d_in[2];
    const float* W        = (const float*)d_in[3];
    const float* a        = (const float*)d_in[4];
    float*       out      = (float*)d_out;

    hipLaunchKernelGGL(fused_kernel, dim3(N_BLOCKS), dim3(1024), 0, stream,
                       x, pos_head, pos_tail, W, a, out);
}